// Round 1
// baseline (153.954 us; speedup 1.0000x reference)
//
#include <hip/hip_runtime.h>
#include <hip/hip_bf16.h>

#define CHUNK 256
#define MM 50
#define KK 4
#define STATE (MM*KK)   // 200
#define ASTRIDE 51      // padded stride for ALG rows (bank-conflict break)
#define GMAX 832        // supports N up to 212992 at CHUNK=256
#define PF 32           // phase-2 prefetch depth

// ---------------- Phase 1: per-chunk summaries B[m][k] ----------------
// B_g[m,k] = sum over source events j in [l-1, r-2] (l==0: [0, r-2]) with mi[j]==m
//            of exp(-gamma_k * (ti[r-1] - ti[j]))
__global__ __launch_bounds__(256) void phase1(
    const float* __restrict__ ti, const int* __restrict__ mi,
    const float* __restrict__ gamma, float* __restrict__ chunkB,
    float* __restrict__ out0, int N, int G) {
  int g = blockIdx.x, tid = threadIdx.x;
  if (g == 0 && tid == 0) out0[0] = 0.f;   // zero accumulator (d_out poisoned 0xAA)
  int l = g * CHUNK;
  int r = min(N, l + CHUNK);
  __shared__ float Bs[STATE];
  __shared__ float g4[KK];
  if (tid < STATE) Bs[tid] = 0.f;
  if (tid < KK) g4[tid] = gamma[tid];
  __syncthreads();
  float t_end = ti[r - 1];
  int j0 = (g == 0) ? 0 : (l - 1);
  int j = j0 + tid;
  if (j <= r - 2) {
    int m = mi[j];
    float dt = t_end - ti[j];
    #pragma unroll
    for (int k = 0; k < KK; ++k)
      atomicAdd(&Bs[m * KK + k], __expf(-g4[k] * dt));
  }
  __syncthreads();
  if (tid < STATE) chunkB[(size_t)g * STATE + tid] = Bs[tid];
}

// ---------------- Phase 2: sequential scan over chunk summaries ----------------
// prefix[g] = state BEFORE chunk g (i.e. S at element g*CHUNK-1). prefix[0]=0.
__global__ __launch_bounds__(256) void phase2(
    const float* __restrict__ ti, const float* __restrict__ gamma,
    const float* __restrict__ chunkB, float* __restrict__ prefix,
    int N, int G) {
  int tid = threadIdx.x;
  __shared__ float tl[GMAX];
  for (int g = tid; g < GMAX; g += blockDim.x) {
    int r = min(N, (g + 1) * CHUNK);
    tl[g] = (g < G) ? ti[r - 1] : 0.f;
  }
  __syncthreads();
  if (tid >= STATE) return;
  int k = tid & 3;
  float gk = gamma[k];
  float S = 0.f;
  prefix[tid] = 0.f;
  float Bcur[PF], Bnxt[PF], Av[PF];
  #pragma unroll
  for (int u = 0; u < PF; ++u)
    Bcur[u] = (u < G) ? chunkB[(size_t)u * STATE + tid] : 0.f;
  for (int base = 0; base < G; base += PF) {
    // prefetch next batch of B (independent of the scan chain)
    #pragma unroll
    for (int u = 0; u < PF; ++u) {
      int gg = base + PF + u;
      Bnxt[u] = (gg < G) ? chunkB[(size_t)gg * STATE + tid] : 0.f;
    }
    // precompute decay factors (independent of the scan chain)
    #pragma unroll
    for (int u = 0; u < PF; ++u) {
      int gg = base + u;
      int gp = (gg > 0) ? gg - 1 : 0;
      float a = __expf(-gk * (tl[min(gg, GMAX - 1)] - tl[gp]));
      Av[u] = (gg == 0) ? 0.f : a;   // g==0: S is 0 anyway
    }
    // the serial FMA chain
    #pragma unroll
    for (int u = 0; u < PF; ++u) {
      int gg = base + u;
      if (gg < G) {
        S = Av[u] * S + Bcur[u];
        if (gg + 1 < G) prefix[(size_t)(gg + 1) * STATE + tid] = S;
      }
    }
    #pragma unroll
    for (int u = 0; u < PF; ++u) Bcur[u] = Bnxt[u];
  }
}

// ---------------- Phase 3: per-event lambda + log-sum ----------------
__global__ __launch_bounds__(256) void phase3(
    const float* __restrict__ ti, const int* __restrict__ mi,
    const float* __restrict__ mu, const float* __restrict__ alpha,
    const float* __restrict__ gamma, const float* __restrict__ prefix,
    float* __restrict__ out, int N, int G) {
  int g = blockIdx.x, tid = threadIdx.x;
  int l = g * CHUNK;
  int r = min(N, l + CHUNK);
  int cnt = r - l;

  __shared__ float4 ALG[MM * ASTRIDE];  // [c_n*ASTRIDE + c_j] -> gamma_k*alpha[k][c_n][c_j], k in lanes of float4
  __shared__ float4 Fj[CHUNK];          // exp(+gamma_k*(t_j - t_ref)) per source slot
  __shared__ int    cj[CHUNK];          // source marks
  __shared__ float4 Sin[MM];            // incoming state [m] -> k
  __shared__ float4 V[MM];              // V[c][k] = sum_m ALG[c][m][k] * Sin[m][k]
  __shared__ float  red[256];

  float gk0 = gamma[0], gk1 = gamma[1], gk2 = gamma[2], gk3 = gamma[3];

  // stage gamma-scaled alpha, transposed to [c][c'][k] float4
  for (int idx = tid; idx < KK * MM * MM; idx += 256) {
    int k = idx / (MM * MM);
    int rem = idx - k * MM * MM;
    int c = rem / MM;
    int cp = rem - c * MM;
    float gk = (k == 0) ? gk0 : (k == 1) ? gk1 : (k == 2) ? gk2 : gk3;
    ((float*)&ALG[c * ASTRIDE + cp])[k] = gk * alpha[idx];
  }
  // incoming prefix state (float4-aligned: 200 floats * 4B * g is 16B-multiple)
  const float4* pf4 = (const float4*)(prefix + (size_t)g * STATE);
  if (tid < MM) Sin[tid] = pf4[tid];

  // source staging
  int j0 = (g == 0) ? 0 : (l - 1);
  int scnt = (r - 1) - j0;          // number of source slots
  float t_ref = ti[j0];
  if (tid < scnt) {
    int j = j0 + tid;
    float tj = ti[j] - t_ref;
    cj[tid] = mi[j];
    Fj[tid] = make_float4(__expf(gk0 * tj), __expf(gk1 * tj),
                          __expf(gk2 * tj), __expf(gk3 * tj));
  }
  __syncthreads();

  // V[c][k] = sum_m ALG[c][m][k] * Sin[m][k]
  if (tid < MM) {
    float4 v = make_float4(0.f, 0.f, 0.f, 0.f);
    #pragma unroll 5
    for (int m = 0; m < MM; ++m) {
      float4 a = ALG[tid * ASTRIDE + m];
      float4 s = Sin[m];
      v.x += a.x * s.x; v.y += a.y * s.y; v.z += a.z * s.z; v.w += a.w * s.w;
    }
    V[tid] = v;
  }
  __syncthreads();

  float local = 0.f;
  if (tid < cnt) {
    int n = l + tid;
    int c_n = mi[n];
    float tn = ti[n] - t_ref;
    float4 E = make_float4(__expf(-gk0 * tn), __expf(-gk1 * tn),
                           __expf(-gk2 * tn), __expf(-gk3 * tn));
    float4 acc = V[c_n];                  // prefix contribution (pre-E)
    int steps = (g == 0) ? tid : tid + 1; // sources j0..n-1
    const float4* arow = &ALG[c_n * ASTRIDE];
    for (int s = 0; s < steps; ++s) {
      float4 a = arow[cj[s]];
      float4 f = Fj[s];
      acc.x += a.x * f.x; acc.y += a.y * f.y;
      acc.z += a.z * f.z; acc.w += a.w * f.w;
    }
    float lam = mu[n] + E.x * acc.x + E.y * acc.y + E.z * acc.z + E.w * acc.w;
    local = __logf(lam);
  }
  red[tid] = local;
  __syncthreads();
  for (int off = 128; off > 0; off >>= 1) {
    if (tid < off) red[tid] += red[tid + off];
    __syncthreads();
  }
  if (tid == 0) atomicAdd(out, red[0]);
}

extern "C" void kernel_launch(void* const* d_in, const int* in_sizes, int n_in,
                              void* d_out, int out_size, void* d_ws, size_t ws_size,
                              hipStream_t stream) {
  const float* ti    = (const float*)d_in[0];
  const int*   mi    = (const int*)d_in[1];
  const float* mu    = (const float*)d_in[2];
  const float* alpha = (const float*)d_in[3];
  const float* gamma = (const float*)d_in[4];
  float* out = (float*)d_out;
  int N = in_sizes[0];
  int G = (N + CHUNK - 1) / CHUNK;
  float* chunkB = (float*)d_ws;                    // G*200 floats
  float* prefix = chunkB + (size_t)G * STATE;      // G*200 floats

  phase1<<<G, 256, 0, stream>>>(ti, mi, gamma, chunkB, out, N, G);
  phase2<<<1, 256, 0, stream>>>(ti, gamma, chunkB, prefix, N, G);
  phase3<<<G, 256, 0, stream>>>(ti, mi, mu, alpha, gamma, prefix, out, N, G);
}

// Round 2
// 117.195 us; speedup vs baseline: 1.3137x; 1.3137x over previous
//
#include <hip/hip_runtime.h>
#include <hip/hip_bf16.h>

#define CHUNK 256
#define MM 50
#define KK 4
#define STATE (MM*KK)   // 200
#define ASTRIDE 51      // padded stride for ALG rows (bank-conflict break)
#define SUP 32          // chunks per super-chunk
#define NSMAX 26        // max super-chunks (G<=832)

// ---------------- Phase 1: per-chunk summaries B[m][k] ----------------
// B_g[m,k] = sum over source events j in [l-1, r-2] (l==0: [0, r-2]) with mi[j]==m
//            of exp(-gamma_k * (ti[r-1] - ti[j]))
__global__ __launch_bounds__(256) void phase1(
    const float* __restrict__ ti, const int* __restrict__ mi,
    const float* __restrict__ gamma, float* __restrict__ chunkB,
    float* __restrict__ out0, int N, int G) {
  int g = blockIdx.x, tid = threadIdx.x;
  if (g == 0 && tid == 0) out0[0] = 0.f;   // zero accumulator (d_out poisoned 0xAA)
  int l = g * CHUNK;
  int r = min(N, l + CHUNK);
  __shared__ float Bs[STATE];
  __shared__ float g4[KK];
  if (tid < STATE) Bs[tid] = 0.f;
  if (tid < KK) g4[tid] = gamma[tid];
  __syncthreads();
  float t_end = ti[r - 1];
  int j0 = (g == 0) ? 0 : (l - 1);
  int j = j0 + tid;
  if (j <= r - 2) {
    int m = mi[j];
    float dt = t_end - ti[j];
    #pragma unroll
    for (int k = 0; k < KK; ++k)
      atomicAdd(&Bs[m * KK + k], __expf(-g4[k] * dt));
  }
  __syncthreads();
  if (tid < STATE) chunkB[(size_t)g * STATE + tid] = Bs[tid];
}

// ---------------- Phase 2a: per-super-chunk local scan ----------------
// localpref[g] = contribution to prefix[g] from chunks within the same super-chunk
//                (rebased at te[g-1]); superB[s] = full-super summary (rebased at te[last(s)])
__global__ __launch_bounds__(256) void phase2a(
    const float* __restrict__ ti, const float* __restrict__ gamma,
    const float* __restrict__ chunkB, float* __restrict__ localpref,
    float* __restrict__ superB, int N, int G) {
  int s = blockIdx.x, tid = threadIdx.x;
  int g0 = s * SUP;
  int gN = min(G, g0 + SUP) - g0;   // chunks in this super-chunk
  __shared__ float te[SUP + 1];     // te[u+1] = end time of chunk g0+u; te[0] = end of g0-1
  if (tid <= SUP) {
    int gg = g0 + tid;              // te[tid] corresponds to chunk gg-1
    te[tid] = (gg == 0) ? ti[0] : ti[min(N, gg * CHUNK) - 1];
  }
  __syncthreads();
  if (tid >= STATE) return;
  float gk = gamma[tid & 3];
  float B[SUP];
  #pragma unroll
  for (int u = 0; u < SUP; ++u)
    B[u] = (u < gN) ? chunkB[(size_t)(g0 + u) * STATE + tid] : 0.f;
  float S = 0.f;
  #pragma unroll
  for (int u = 0; u < SUP; ++u) {
    if (u < gN) {
      localpref[(size_t)(g0 + u) * STATE + tid] = S;
      if (u == 0) {
        S = B[0];                    // S==0, decay irrelevant
      } else {
        float a = __expf(-gk * (te[u + 1] - te[u]));
        S = a * S + B[u];
      }
    }
  }
  superB[(size_t)s * STATE + tid] = S;
}

// ---------------- Phase 2b: scan over super-chunk summaries ----------------
// superpref[s] = state before super-chunk s (rebased at te[last(s-1)]); superpref[0]=0
__global__ __launch_bounds__(256) void phase2b(
    const float* __restrict__ ti, const float* __restrict__ gamma,
    const float* __restrict__ superB, float* __restrict__ superpref,
    int N, int nS) {
  int tid = threadIdx.x;
  __shared__ float tlast[NSMAX];    // tlast[s] = end time of last chunk of super s
  if (tid < NSMAX)
    tlast[tid] = ti[min(SUP * (tid + 1) * CHUNK, N) - 1];
  __syncthreads();
  if (tid >= STATE) return;
  float gk = gamma[tid & 3];
  float B[NSMAX];
  #pragma unroll
  for (int s = 0; s < NSMAX; ++s)
    B[s] = (s < nS) ? superB[(size_t)s * STATE + tid] : 0.f;
  float S = 0.f;
  superpref[tid] = 0.f;
  #pragma unroll
  for (int s = 0; s < NSMAX; ++s) {
    if (s < nS) {
      if (s == 0) {
        S = B[0];
      } else {
        float a = __expf(-gk * (tlast[s] - tlast[s - 1]));
        S = a * S + B[s];
      }
      if (s + 1 < nS) superpref[(size_t)(s + 1) * STATE + tid] = S;
    }
  }
}

// ---------------- Phase 3: per-event lambda + log-sum ----------------
__global__ __launch_bounds__(256) void phase3(
    const float* __restrict__ ti, const int* __restrict__ mi,
    const float* __restrict__ mu, const float* __restrict__ alpha,
    const float* __restrict__ gamma, const float* __restrict__ localpref,
    const float* __restrict__ superpref, float* __restrict__ out, int N, int G) {
  int g = blockIdx.x, tid = threadIdx.x;
  int l = g * CHUNK;
  int r = min(N, l + CHUNK);
  int cnt = r - l;
  int sup = g / SUP;

  __shared__ float4 ALG[MM * ASTRIDE];  // [c_n*ASTRIDE + c_j] -> gamma_k*alpha[k][c_n][c_j]
  __shared__ float4 Fj[CHUNK];          // exp(+gamma_k*(t_j - t_ref)) per source slot
  __shared__ int    cj[CHUNK];          // source marks
  __shared__ float4 Sin[MM];            // incoming full prefix state [m] -> k
  __shared__ float4 V[MM];              // V[c][k] = sum_m ALG[c][m][k] * Sin[m][k]
  __shared__ float  red[256];

  float gk0 = gamma[0], gk1 = gamma[1], gk2 = gamma[2], gk3 = gamma[3];

  // stage gamma-scaled alpha, transposed to [c][c'][k] float4
  for (int idx = tid; idx < KK * MM * MM; idx += 256) {
    int k = idx / (MM * MM);
    int rem = idx - k * MM * MM;
    int c = rem / MM;
    int cp = rem - c * MM;
    float gk = (k == 0) ? gk0 : (k == 1) ? gk1 : (k == 2) ? gk2 : gk3;
    ((float*)&ALG[c * ASTRIDE + cp])[k] = gk * alpha[idx];
  }
  // reconstruct full prefix: Sin = localpref[g] + D * superpref[sup]
  if (tid < MM) {
    float t_hi = (g > 0) ? ti[(size_t)g * CHUNK - 1] : ti[0];
    float t_lo = (sup > 0) ? ti[(size_t)sup * SUP * CHUNK - 1] : ti[0];
    float dt = t_hi - t_lo;
    float4 D = make_float4(__expf(-gk0 * dt), __expf(-gk1 * dt),
                           __expf(-gk2 * dt), __expf(-gk3 * dt));
    const float4* lp4 = (const float4*)(localpref + (size_t)g * STATE);
    const float4* sp4 = (const float4*)(superpref + (size_t)sup * STATE);
    float4 lp = lp4[tid], sp = sp4[tid];
    Sin[tid] = make_float4(lp.x + D.x * sp.x, lp.y + D.y * sp.y,
                           lp.z + D.z * sp.z, lp.w + D.w * sp.w);
  }

  // source staging
  int j0 = (g == 0) ? 0 : (l - 1);
  int scnt = (r - 1) - j0;          // number of source slots
  float t_ref = ti[j0];
  if (tid < scnt) {
    int j = j0 + tid;
    float tj = ti[j] - t_ref;
    cj[tid] = mi[j];
    Fj[tid] = make_float4(__expf(gk0 * tj), __expf(gk1 * tj),
                          __expf(gk2 * tj), __expf(gk3 * tj));
  }
  __syncthreads();

  // V[c][k] = sum_m ALG[c][m][k] * Sin[m][k]
  if (tid < MM) {
    float4 v = make_float4(0.f, 0.f, 0.f, 0.f);
    #pragma unroll 5
    for (int m = 0; m < MM; ++m) {
      float4 a = ALG[tid * ASTRIDE + m];
      float4 s = Sin[m];
      v.x += a.x * s.x; v.y += a.y * s.y; v.z += a.z * s.z; v.w += a.w * s.w;
    }
    V[tid] = v;
  }
  __syncthreads();

  float local = 0.f;
  if (tid < cnt) {
    int n = l + tid;
    int c_n = mi[n];
    float tn = ti[n] - t_ref;
    float4 E = make_float4(__expf(-gk0 * tn), __expf(-gk1 * tn),
                           __expf(-gk2 * tn), __expf(-gk3 * tn));
    float4 acc = V[c_n];                  // prefix contribution (pre-E)
    int steps = (g == 0) ? tid : tid + 1; // sources j0..n-1
    const float4* arow = &ALG[c_n * ASTRIDE];
    #pragma unroll 4
    for (int s = 0; s < steps; ++s) {
      float4 a = arow[cj[s]];
      float4 f = Fj[s];
      acc.x += a.x * f.x; acc.y += a.y * f.y;
      acc.z += a.z * f.z; acc.w += a.w * f.w;
    }
    float lam = mu[n] + E.x * acc.x + E.y * acc.y + E.z * acc.z + E.w * acc.w;
    local = __logf(lam);
  }
  red[tid] = local;
  __syncthreads();
  for (int off = 128; off > 0; off >>= 1) {
    if (tid < off) red[tid] += red[tid + off];
    __syncthreads();
  }
  if (tid == 0) atomicAdd(out, red[0]);
}

extern "C" void kernel_launch(void* const* d_in, const int* in_sizes, int n_in,
                              void* d_out, int out_size, void* d_ws, size_t ws_size,
                              hipStream_t stream) {
  const float* ti    = (const float*)d_in[0];
  const int*   mi    = (const int*)d_in[1];
  const float* mu    = (const float*)d_in[2];
  const float* alpha = (const float*)d_in[3];
  const float* gamma = (const float*)d_in[4];
  float* out = (float*)d_out;
  int N = in_sizes[0];
  int G = (N + CHUNK - 1) / CHUNK;
  int nS = (G + SUP - 1) / SUP;
  float* chunkB    = (float*)d_ws;                       // G*200 floats
  float* localpref = chunkB + (size_t)G * STATE;         // G*200 floats
  float* superB    = localpref + (size_t)G * STATE;      // nS*200 floats
  float* superpref = superB + (size_t)NSMAX * STATE;     // nS*200 floats

  phase1<<<G, 256, 0, stream>>>(ti, mi, gamma, chunkB, out, N, G);
  phase2a<<<nS, 256, 0, stream>>>(ti, gamma, chunkB, localpref, superB, N, G);
  phase2b<<<1, 256, 0, stream>>>(ti, gamma, superB, superpref, N, nS);
  phase3<<<G, 256, 0, stream>>>(ti, mi, mu, alpha, gamma, localpref, superpref, out, N, G);
}

// Round 3
// 106.142 us; speedup vs baseline: 1.4505x; 1.1041x over previous
//
#include <hip/hip_runtime.h>
#include <hip/hip_bf16.h>

#define CHUNK 256
#define MM 50
#define KK 4
#define STATE (MM*KK)   // 200
#define ASTRIDE 51      // padded row stride for ALGh (uint2 units)
#define SUP 32          // chunks per super-chunk
#define NSMAX 26        // max super-chunks (G<=832)

__device__ __forceinline__ unsigned short f2bf(float x) {
  unsigned u = __float_as_uint(x);
  u += 0x7fffu + ((u >> 16) & 1u);   // round-to-nearest-even
  return (unsigned short)(u >> 16);
}

// ---------------- Phase 1: per-chunk summaries B[m][k] ----------------
__global__ __launch_bounds__(256) void phase1(
    const float* __restrict__ ti, const int* __restrict__ mi,
    const float* __restrict__ gamma, float* __restrict__ chunkB,
    float* __restrict__ out0, int N, int G) {
  int g = blockIdx.x, tid = threadIdx.x;
  if (g == 0 && tid == 0) out0[0] = 0.f;   // zero accumulator (d_out poisoned 0xAA)
  int l = g * CHUNK;
  int r = min(N, l + CHUNK);
  __shared__ float Bs[STATE];
  __shared__ float g4[KK];
  if (tid < STATE) Bs[tid] = 0.f;
  if (tid < KK) g4[tid] = gamma[tid];
  __syncthreads();
  float t_end = ti[r - 1];
  int j0 = (g == 0) ? 0 : (l - 1);
  int j = j0 + tid;
  if (j <= r - 2) {
    int m = mi[j];
    float dt = t_end - ti[j];
    #pragma unroll
    for (int k = 0; k < KK; ++k)
      atomicAdd(&Bs[m * KK + k], __expf(-g4[k] * dt));
  }
  __syncthreads();
  if (tid < STATE) chunkB[(size_t)g * STATE + tid] = Bs[tid];
}

// ---------------- Phase 2a: per-super-chunk local scan ----------------
__global__ __launch_bounds__(256) void phase2a(
    const float* __restrict__ ti, const float* __restrict__ gamma,
    const float* __restrict__ chunkB, float* __restrict__ localpref,
    float* __restrict__ superB, int N, int G) {
  int s = blockIdx.x, tid = threadIdx.x;
  int g0 = s * SUP;
  int gN = min(G, g0 + SUP) - g0;
  __shared__ float te[SUP + 1];
  if (tid <= SUP) {
    int gg = g0 + tid;
    te[tid] = (gg == 0) ? ti[0] : ti[min(N, gg * CHUNK) - 1];
  }
  __syncthreads();
  if (tid >= STATE) return;
  float gk = gamma[tid & 3];
  float B[SUP];
  #pragma unroll
  for (int u = 0; u < SUP; ++u)
    B[u] = (u < gN) ? chunkB[(size_t)(g0 + u) * STATE + tid] : 0.f;
  float S = 0.f;
  #pragma unroll
  for (int u = 0; u < SUP; ++u) {
    if (u < gN) {
      localpref[(size_t)(g0 + u) * STATE + tid] = S;
      if (u == 0) {
        S = B[0];
      } else {
        float a = __expf(-gk * (te[u + 1] - te[u]));
        S = a * S + B[u];
      }
    }
  }
  superB[(size_t)s * STATE + tid] = S;
}

// ---------------- Phase 2b: scan over super-chunk summaries ----------------
__global__ __launch_bounds__(256) void phase2b(
    const float* __restrict__ ti, const float* __restrict__ gamma,
    const float* __restrict__ superB, float* __restrict__ superpref,
    int N, int nS) {
  int tid = threadIdx.x;
  __shared__ float tlast[NSMAX];
  if (tid < NSMAX)
    tlast[tid] = ti[min(SUP * (tid + 1) * CHUNK, N) - 1];
  __syncthreads();
  if (tid >= STATE) return;
  float gk = gamma[tid & 3];
  float B[NSMAX];
  #pragma unroll
  for (int s = 0; s < NSMAX; ++s)
    B[s] = (s < nS) ? superB[(size_t)s * STATE + tid] : 0.f;
  float S = 0.f;
  superpref[tid] = 0.f;
  #pragma unroll
  for (int s = 0; s < NSMAX; ++s) {
    if (s < nS) {
      if (s == 0) S = B[0];
      else {
        float a = __expf(-gk * (tlast[s] - tlast[s - 1]));
        S = a * S + B[s];
      }
      if (s + 1 < nS) superpref[(size_t)(s + 1) * STATE + tid] = S;
    }
  }
}

// ---------------- Phase 3: per-event lambda + log-sum (two-level) ----------------
__global__ __launch_bounds__(256) void phase3(
    const float* __restrict__ ti, const int* __restrict__ mi,
    const float* __restrict__ mu, const float* __restrict__ alpha,
    const float* __restrict__ gamma, const float* __restrict__ localpref,
    const float* __restrict__ superpref, float* __restrict__ out, int N, int G) {
  int g = blockIdx.x, tid = threadIdx.x;
  int l = g * CHUNK;
  int r = min(N, l + CHUNK);
  int cnt = r - l;
  int sup = g / SUP;

  __shared__ uint2  ALGh[MM * ASTRIDE]; // bf16x4 gamma_k*alpha[k][c][c'] ~20.4KB
  __shared__ float4 Fj[CHUNK];          // exp(+gamma_k*(t_j - t_ref)), slot s = j-(l-1)
  __shared__ int    cj[CHUNK];          // source marks per slot
  __shared__ float  Q[4][STATE];        // quarter scatters -> in-place WB prefix
  __shared__ float  red[256];

  float gk0 = gamma[0], gk1 = gamma[1], gk2 = gamma[2], gk3 = gamma[3];

  // zero quarter buckets
  for (int i = tid; i < 4 * STATE; i += 256) ((float*)Q)[i] = 0.f;

  // stage bf16-packed gamma*alpha: entry (c,cp) <- {k0..k3}
  for (int e = tid; e < MM * MM; e += 256) {
    int c = e / MM, cp = e - c * MM;
    float a0 = gk0 * alpha[e];
    float a1 = gk1 * alpha[2500 + e];
    float a2 = gk2 * alpha[5000 + e];
    float a3 = gk3 * alpha[7500 + e];
    ALGh[c * ASTRIDE + cp] =
        make_uint2((unsigned)f2bf(a0) | ((unsigned)f2bf(a1) << 16),
                   (unsigned)f2bf(a2) | ((unsigned)f2bf(a3) << 16));
  }

  // own-source staging: slot s = tid corresponds to source j = l-1+tid
  int j = l - 1 + tid;
  float t_ref = ti[(g == 0) ? 0 : (l - 1)];
  float4 myF = make_float4(0.f, 0.f, 0.f, 0.f);
  int myc = 0;
  bool valid = (j >= 0) && (j <= r - 2);
  if (valid) {
    myc = mi[j];
    float tj = ti[j] - t_ref;
    myF = make_float4(__expf(gk0 * tj), __expf(gk1 * tj),
                      __expf(gk2 * tj), __expf(gk3 * tj));
  }
  cj[tid] = myc;
  Fj[tid] = myF;
  __syncthreads();

  // scatter own F into this quarter's mark bucket
  if (valid) {
    float* q = &Q[tid >> 6][myc * KK];
    atomicAdd(q + 0, myF.x); atomicAdd(q + 1, myF.y);
    atomicAdd(q + 2, myF.z); atomicAdd(q + 3, myF.w);
  }
  __syncthreads();

  // WB[t] = Sin + sum_{q<t} Q[q], in place (thread tid owns component tid)
  if (tid < STATE) {
    float gk = gamma[tid & 3];
    float t_hi = (g > 0) ? ti[(size_t)g * CHUNK - 1] : ti[0];
    float t_lo = (sup > 0) ? ti[(size_t)sup * SUP * CHUNK - 1] : ti[0];
    float D = __expf(-gk * (t_hi - t_lo));
    float sin_v = localpref[(size_t)g * STATE + tid]
                + D * superpref[(size_t)sup * STATE + tid];
    float q0 = Q[0][tid], q1 = Q[1][tid], q2 = Q[2][tid];
    Q[0][tid] = sin_v;
    Q[1][tid] = sin_v + q0;
    Q[2][tid] = sin_v + q0 + q1;
    Q[3][tid] = sin_v + q0 + q1 + q2;
  }
  __syncthreads();

  float local = 0.f;
  if (tid < cnt) {
    int n = l + tid;
    int c_n = mi[n];
    const uint2* arow = &ALGh[c_n * ASTRIDE];
    const float4* wb = (const float4*)&Q[tid >> 6][0];  // rows are 800B -> 16B aligned
    float4 acc = make_float4(0.f, 0.f, 0.f, 0.f);
    // prefix contraction over marks (WB read is a wave-uniform broadcast)
    #pragma unroll 2
    for (int m = 0; m < MM; ++m) {
      uint2 p = arow[m];
      float4 w = wb[m];
      acc.x += __uint_as_float(p.x << 16)          * w.x;
      acc.y += __uint_as_float(p.x & 0xffff0000u)  * w.y;
      acc.z += __uint_as_float(p.y << 16)          * w.z;
      acc.w += __uint_as_float(p.y & 0xffff0000u)  * w.w;
    }
    // intra-sub-chunk pairwise (<=64 steps)
    #pragma unroll 4
    for (int s = (tid & ~63); s <= tid; ++s) {
      uint2 p = arow[cj[s]];
      float4 f = Fj[s];
      acc.x += __uint_as_float(p.x << 16)          * f.x;
      acc.y += __uint_as_float(p.x & 0xffff0000u)  * f.y;
      acc.z += __uint_as_float(p.y << 16)          * f.z;
      acc.w += __uint_as_float(p.y & 0xffff0000u)  * f.w;
    }
    float tn = ti[n] - t_ref;
    float lam = mu[n]
              + __expf(-gk0 * tn) * acc.x + __expf(-gk1 * tn) * acc.y
              + __expf(-gk2 * tn) * acc.z + __expf(-gk3 * tn) * acc.w;
    local = __logf(lam);
  }
  red[tid] = local;
  __syncthreads();
  for (int off = 128; off > 0; off >>= 1) {
    if (tid < off) red[tid] += red[tid + off];
    __syncthreads();
  }
  if (tid == 0) atomicAdd(out, red[0]);
}

extern "C" void kernel_launch(void* const* d_in, const int* in_sizes, int n_in,
                              void* d_out, int out_size, void* d_ws, size_t ws_size,
                              hipStream_t stream) {
  const float* ti    = (const float*)d_in[0];
  const int*   mi    = (const int*)d_in[1];
  const float* mu    = (const float*)d_in[2];
  const float* alpha = (const float*)d_in[3];
  const float* gamma = (const float*)d_in[4];
  float* out = (float*)d_out;
  int N = in_sizes[0];
  int G = (N + CHUNK - 1) / CHUNK;
  int nS = (G + SUP - 1) / SUP;
  float* chunkB    = (float*)d_ws;                       // G*200 floats
  float* localpref = chunkB + (size_t)G * STATE;         // G*200 floats
  float* superB    = localpref + (size_t)G * STATE;      // nS*200 floats
  float* superpref = superB + (size_t)NSMAX * STATE;     // nS*200 floats

  phase1<<<G, 256, 0, stream>>>(ti, mi, gamma, chunkB, out, N, G);
  phase2a<<<nS, 256, 0, stream>>>(ti, gamma, chunkB, localpref, superB, N, G);
  phase2b<<<1, 256, 0, stream>>>(ti, gamma, superB, superpref, N, nS);
  phase3<<<G, 256, 0, stream>>>(ti, mi, mu, alpha, gamma, localpref, superpref, out, N, G);
}